// Round 4
// baseline (454.069 us; speedup 1.0000x reference)
//
#include <hip/hip_runtime.h>
#include <math.h>

// CorollaryResonanceBank — two-kernel implementation.
//
// Shapes: B=256, C=64, T=2048, R=16, TIME_BINS=128, WIN=16.
// Memory-bound: 402.7 MB read once. Round-2 single-kernel ran 450 us
// (0.89 TB/s) — only 8 waves/CU, load latency unhidden. Fix: split the
// channel reduction 4-ways (CS=4) and time 2-ways (TS=2) -> 2048 blocks
// = 32 waves/CU; Little's law saturates HBM even with 1 load in flight
// per wave. K1 writes raw window partials (B,4,128,CS) to ws; K2 combines,
// computes scale, runs the 128-step resonate-and-fire scan.

#define NB 256
#define NC 64
#define NT 2048
#define NR 16
#define NTB 128
#define NWIN 16
#define CS 4               // channel splits
#define TS 2               // time splits
#define CCH (NC / CS)      // 16 channels per K1 block
#define TCH (NT / TS)      // 1024 t per K1 block
#define WCH (TCH / NWIN)   // 64 windows per K1 block

// ---------------- K1: streaming c-reduction + window partial sums ----------
__global__ __launch_bounds__(256) void crb_reduce_k1(
    const float* __restrict__ transmit,   // (B,C,T)
    const float* __restrict__ receive,    // (B,2,C,T)
    float* __restrict__ part)             // ws: (B,4,NTB,CS) raw window sums
{
    const int blk  = blockIdx.x;
    const int b    = blk / (TS * CS);
    const int rem  = blk % (TS * CS);
    const int ts_i = rem / CS;
    const int cs_i = rem % CS;
    const int tid  = threadIdx.x;
    const int t0   = ts_i * TCH + tid * 4;   // 4 consecutive t per thread
    const int c0   = cs_i * CCH;

    const float4* tp = reinterpret_cast<const float4*>(
        transmit + ((size_t)b * NC + c0) * NT + t0);
    const float4* lp = reinterpret_cast<const float4*>(
        receive + (((size_t)b * 2 + 0) * NC + c0) * NT + t0);
    const float4* rp = reinterpret_cast<const float4*>(
        receive + (((size_t)b * 2 + 1) * NC + c0) * NT + t0);
    const int row = NT / 4;                  // float4 stride between c rows

    float ts0=0.f, ts1=0.f, ts2=0.f, ts3=0.f;   // transmit sum
    float ls0=0.f, ls1=0.f, ls2=0.f, ls3=0.f;   // left sum
    float rs0=0.f, rs1=0.f, rs2=0.f, rs3=0.f;   // right sum
    float es0=0.f, es1=0.f, es2=0.f, es3=0.f;   // elevation sum

    #pragma unroll 8
    for (int i = 0; i < CCH; ++i) {
        const float ch = fmaf((float)(c0 + i), 2.0f / 63.0f, -1.0f);
        const float4 tv = tp[i * row];
        const float4 lv = lp[i * row];
        const float4 rv = rp[i * row];
        ts0 += tv.x; ts1 += tv.y; ts2 += tv.z; ts3 += tv.w;
        ls0 += lv.x; ls1 += lv.y; ls2 += lv.z; ls3 += lv.w;
        rs0 += rv.x; rs1 += rv.y; rs2 += rv.z; rs3 += rv.w;
        es0 = fmaf(lv.x + rv.x, ch, es0);
        es1 = fmaf(lv.y + rv.y, ch, es1);
        es2 = fmaf(lv.z + rv.z, ch, es2);
        es3 = fmaf(lv.w + rv.w, ch, es3);
    }

    // per-thread sums over its 4 t
    float t4 = (ts0 + ts1) + (ts2 + ts3);
    float l4 = (ls0 + ls1) + (ls2 + ls3);
    float r4 = (rs0 + rs1) + (rs2 + rs3);
    float e4 = (es0 + es1) + (es2 + es3);

    // 16-t window = 4-lane group; butterfly gives full sum to all 4 lanes
    t4 += __shfl_xor(t4, 1); t4 += __shfl_xor(t4, 2);
    l4 += __shfl_xor(l4, 1); l4 += __shfl_xor(l4, 2);
    r4 += __shfl_xor(r4, 1); r4 += __shfl_xor(r4, 2);
    e4 += __shfl_xor(e4, 1); e4 += __shfl_xor(e4, 2);

    // lane q of each 4-group writes quantity q (all lanes active, 1 store each)
    const int q = tid & 3;
    const int w = ts_i * WCH + (tid >> 2);   // global window index 0..127
    const float v = (q == 0) ? t4 : (q == 1) ? l4 : (q == 2) ? r4 : e4;
    part[(((size_t)b * 4 + q) * NTB + w) * CS + cs_i] = v;
}

// ---------------- K2: combine partials, scale, resonate-and-fire scan ------
__global__ __launch_bounds__(128) void crb_scan_k2(
    const float* __restrict__ part,       // (B,4,NTB,CS)
    const float* __restrict__ conv_w,     // (R,3)
    const float* __restrict__ conv_b,     // (R,)
    const float* __restrict__ frequency,  // (R,)
    const float* __restrict__ decay,      // (R,)
    const float* __restrict__ threshold,  // (R,)
    const float* __restrict__ tw,         // scalar
    const float* __restrict__ rw,         // scalar
    float* __restrict__ out)              // (B,R)
{
    const int b   = blockIdx.x;
    const int tid = threadIdx.x;          // 128 threads = 128 windows

    __shared__ float sdw[NTB];
    __shared__ float azw[NTB];
    __shared__ float elw[NTB];
    __shared__ float red[2];
    __shared__ float s_scale;

    // combine the CS=4 partials for window tid (float4 loads, 16B aligned)
    const float4 tq = *reinterpret_cast<const float4*>(
        &part[(((size_t)b * 4 + 0) * NTB + tid) * CS]);
    const float4 lq = *reinterpret_cast<const float4*>(
        &part[(((size_t)b * 4 + 1) * NTB + tid) * CS]);
    const float4 rq = *reinterpret_cast<const float4*>(
        &part[(((size_t)b * 4 + 2) * NTB + tid) * CS]);
    const float4 eq = *reinterpret_cast<const float4*>(
        &part[(((size_t)b * 4 + 3) * NTB + tid) * CS]);
    const float tsum = ((tq.x + tq.y) + (tq.z + tq.w));
    const float lsum = ((lq.x + lq.y) + (lq.z + lq.w));
    const float rsum = ((rq.x + rq.y) + (rq.z + rq.w));
    const float esum = ((eq.x + eq.y) + (eq.z + eq.w));

    const float sp_tw = log1pf(expf(tw[0]));
    const float sp_rw = log1pf(expf(rw[0]));

    const float sd = (sp_rw * 0.5f * (lsum + rsum) - sp_tw * tsum) * (1.0f / NWIN);
    const float az = (lsum - rsum) * (1.0f / NWIN);
    const float el = esum * (1.0f / NWIN);
    sdw[tid] = sd; azw[tid] = az; elw[tid] = el;

    // scale = max(|traces|, 1.0)
    float m = fmaxf(fabsf(sd), fmaxf(fabsf(az), fabsf(el)));
    #pragma unroll
    for (int off = 32; off >= 1; off >>= 1)
        m = fmaxf(m, __shfl_xor(m, off));
    if ((tid & 63) == 0) red[tid >> 6] = m;
    __syncthreads();
    if (tid == 0) s_scale = fmaxf(fmaxf(red[0], red[1]), 1.0f);
    __syncthreads();

    // resonate-and-fire scan, one lane per r
    if (tid < NR) {
        const int r = tid;
        const float inv_scale = 1.0f / s_scale;
        const float w0 = conv_w[r * 3 + 0];
        const float w1 = conv_w[r * 3 + 1];
        const float w2 = conv_w[r * 3 + 2];
        const float bias = conv_b[r];
        const float fr = 0.02f + 0.18f / (1.0f + expf(-frequency[r]));
        const float dc = 0.80f + 0.18f / (1.0f + expf(-decay[r]));
        const float th = 0.35f + 0.75f / (1.0f + expf(-threshold[r]));

        float st = 0.f, vel = 0.f, cnt = 0.f;
        for (int t = 0; t < NTB; ++t) {
            const float cur =
                (sdw[t] * w0 + azw[t] * w1 + elw[t] * w2) * inv_scale + bias;
            vel = dc * vel + cur - fr * st;
            st  = st + fr * vel;
            const float sp = ((st - th) > 0.0f) ? 1.0f : 0.0f;
            st -= sp * th;
            cnt += sp;
        }
        out[(size_t)b * NR + r] = cnt * (1.0f / NTB);
    }
}

extern "C" void kernel_launch(void* const* d_in, const int* in_sizes, int n_in,
                              void* d_out, int out_size, void* d_ws, size_t ws_size,
                              hipStream_t stream) {
    const float* transmit  = (const float*)d_in[0];  // (B,C,T)
    const float* receive   = (const float*)d_in[1];  // (B,2,C,T)
    const float* conv_w    = (const float*)d_in[2];  // (R,3)
    const float* conv_b    = (const float*)d_in[3];  // (R,)
    const float* frequency = (const float*)d_in[4];  // (R,)
    const float* decay     = (const float*)d_in[5];  // (R,)
    const float* threshold = (const float*)d_in[6];  // (R,)
    const float* tw        = (const float*)d_in[7];  // scalar
    const float* rw        = (const float*)d_in[8];  // scalar
    float* out  = (float*)d_out;                     // (B,R) f32
    float* part = (float*)d_ws;                      // (B,4,NTB,CS) = 2 MB

    crb_reduce_k1<<<NB * TS * CS, 256, 0, stream>>>(transmit, receive, part);
    crb_scan_k2<<<NB, 128, 0, stream>>>(part, conv_w, conv_b, frequency,
                                        decay, threshold, tw, rw, out);
}

// Round 6
// 421.836 us; speedup vs baseline: 1.0764x; 1.0764x over previous
//
#include <hip/hip_runtime.h>
#include <math.h>

// CorollaryResonanceBank — two-kernel implementation, round 6.
//
// Shapes: B=256, C=64, T=2048, R=16, TIME_BINS=128, WIN=16.
// Memory-bound: 402.7 MB read once -> ~64 us floor at 6.3 TB/s.
// Round-4 learning: measured dur_us (~450) is dominated by ~360 us of
// harness restore/poison; our kernels are <158 us (absent from top-5
// profiled dispatches). This round: maximally-linear streaming K1 —
// block = (b, 16-channel chunk) reads three contiguous 128 KB regions
// with nontemporal float4 loads (ext_vector_type — the HIP float4 struct
// is rejected by __builtin_nontemporal_load); 1024 blocks x 256 thr,
// 4 blocks/CU. K1 writes raw window partials (B,4,128,CS) to ws; K2
// combines, scales, runs the 128-step resonate-and-fire scan.
// Arithmetic order identical to round-4 (absmax was 0.0).

#define NB 256
#define NC 64
#define NT 2048
#define NR 16
#define NTB 128
#define NWIN 16
#define CS 4               // channel splits
#define CCH (NC / CS)      // 16 channels per K1 block

typedef float f32x4 __attribute__((ext_vector_type(4)));

// ---------------- K1: streaming c-reduction + window partial sums ----------
__global__ __launch_bounds__(256, 4) void crb_reduce_k1(
    const float* __restrict__ transmit,   // (B,C,T)
    const float* __restrict__ receive,    // (B,2,C,T)
    float* __restrict__ part)             // ws: (B,4,NTB,CS) raw window sums
{
    const int blk  = blockIdx.x;          // 0 .. B*CS-1
    const int b    = blk / CS;
    const int cs_i = blk % CS;
    const int tid  = threadIdx.x;
    const int c0   = cs_i * CCH;

    // Base pointers: thread covers t = tid*4 (h=0) and 1024 + tid*4 (h=1)
    // across CCH=16 full rows -> block streams contiguous 128 KB per input.
    const f32x4* tp = reinterpret_cast<const f32x4*>(
        transmit + ((size_t)b * NC + c0) * NT) + tid;
    const f32x4* lp = reinterpret_cast<const f32x4*>(
        receive + (((size_t)b * 2 + 0) * NC + c0) * NT) + tid;
    const f32x4* rp = reinterpret_cast<const f32x4*>(
        receive + (((size_t)b * 2 + 1) * NC + c0) * NT) + tid;
    const int row  = NT / 4;              // 512 f32x4 per row
    const int half = 256;                 // f32x4 offset of second half-row

    // accumulators: [h][elem] for transmit/left/right/elev
    float ts[2][4] = {}, ls[2][4] = {}, rs[2][4] = {}, es[2][4] = {};

    #pragma unroll 4
    for (int i = 0; i < CCH; ++i) {
        const float ch = fmaf((float)(c0 + i), 2.0f / 63.0f, -1.0f);
        const f32x4 tv0 = __builtin_nontemporal_load(tp + i * row);
        const f32x4 tv1 = __builtin_nontemporal_load(tp + i * row + half);
        const f32x4 lv0 = __builtin_nontemporal_load(lp + i * row);
        const f32x4 lv1 = __builtin_nontemporal_load(lp + i * row + half);
        const f32x4 rv0 = __builtin_nontemporal_load(rp + i * row);
        const f32x4 rv1 = __builtin_nontemporal_load(rp + i * row + half);

        #pragma unroll
        for (int e = 0; e < 4; ++e) {
            ts[0][e] += tv0[e];
            ts[1][e] += tv1[e];
            ls[0][e] += lv0[e];
            ls[1][e] += lv1[e];
            rs[0][e] += rv0[e];
            rs[1][e] += rv1[e];
            es[0][e] = fmaf(lv0[e] + rv0[e], ch, es[0][e]);
            es[1][e] = fmaf(lv1[e] + rv1[e], ch, es[1][e]);
        }
    }

    const int q = tid & 3;                // quantity this lane will store
    #pragma unroll
    for (int h = 0; h < 2; ++h) {
        // per-thread sums over its 4 t (sequential order, matches reference tree)
        float t4 = (ts[h][0] + ts[h][1]) + (ts[h][2] + ts[h][3]);
        float l4 = (ls[h][0] + ls[h][1]) + (ls[h][2] + ls[h][3]);
        float r4 = (rs[h][0] + rs[h][1]) + (rs[h][2] + rs[h][3]);
        float e4 = (es[h][0] + es[h][1]) + (es[h][2] + es[h][3]);

        // 16-t window = 4-lane group butterfly
        t4 += __shfl_xor(t4, 1); t4 += __shfl_xor(t4, 2);
        l4 += __shfl_xor(l4, 1); l4 += __shfl_xor(l4, 2);
        r4 += __shfl_xor(r4, 1); r4 += __shfl_xor(r4, 2);
        e4 += __shfl_xor(e4, 1); e4 += __shfl_xor(e4, 2);

        const int w = h * 64 + (tid >> 2);   // window index 0..127
        const float v = (q == 0) ? t4 : (q == 1) ? l4 : (q == 2) ? r4 : e4;
        part[(((size_t)b * 4 + q) * NTB + w) * CS + cs_i] = v;
    }
}

// ---------------- K2: combine partials, scale, resonate-and-fire scan ------
__global__ __launch_bounds__(128) void crb_scan_k2(
    const float* __restrict__ part,       // (B,4,NTB,CS)
    const float* __restrict__ conv_w,     // (R,3)
    const float* __restrict__ conv_b,     // (R,)
    const float* __restrict__ frequency,  // (R,)
    const float* __restrict__ decay,      // (R,)
    const float* __restrict__ threshold,  // (R,)
    const float* __restrict__ tw,         // scalar
    const float* __restrict__ rw,         // scalar
    float* __restrict__ out)              // (B,R)
{
    const int b   = blockIdx.x;
    const int tid = threadIdx.x;          // 128 threads = 128 windows

    __shared__ float sdw[NTB];
    __shared__ float azw[NTB];
    __shared__ float elw[NTB];
    __shared__ float red[2];
    __shared__ float s_scale;

    // combine the CS=4 partials for window tid (float4 loads, 16B aligned)
    const float4 tq = *reinterpret_cast<const float4*>(
        &part[(((size_t)b * 4 + 0) * NTB + tid) * CS]);
    const float4 lq = *reinterpret_cast<const float4*>(
        &part[(((size_t)b * 4 + 1) * NTB + tid) * CS]);
    const float4 rq = *reinterpret_cast<const float4*>(
        &part[(((size_t)b * 4 + 2) * NTB + tid) * CS]);
    const float4 eq = *reinterpret_cast<const float4*>(
        &part[(((size_t)b * 4 + 3) * NTB + tid) * CS]);
    const float tsum = ((tq.x + tq.y) + (tq.z + tq.w));
    const float lsum = ((lq.x + lq.y) + (lq.z + lq.w));
    const float rsum = ((rq.x + rq.y) + (rq.z + rq.w));
    const float esum = ((eq.x + eq.y) + (eq.z + eq.w));

    const float sp_tw = log1pf(expf(tw[0]));
    const float sp_rw = log1pf(expf(rw[0]));

    const float sd = (sp_rw * 0.5f * (lsum + rsum) - sp_tw * tsum) * (1.0f / NWIN);
    const float az = (lsum - rsum) * (1.0f / NWIN);
    const float el = esum * (1.0f / NWIN);
    sdw[tid] = sd; azw[tid] = az; elw[tid] = el;

    // scale = max(|traces|, 1.0)
    float m = fmaxf(fabsf(sd), fmaxf(fabsf(az), fabsf(el)));
    #pragma unroll
    for (int off = 32; off >= 1; off >>= 1)
        m = fmaxf(m, __shfl_xor(m, off));
    if ((tid & 63) == 0) red[tid >> 6] = m;
    __syncthreads();
    if (tid == 0) s_scale = fmaxf(fmaxf(red[0], red[1]), 1.0f);
    __syncthreads();

    // resonate-and-fire scan, one lane per r
    if (tid < NR) {
        const int r = tid;
        const float inv_scale = 1.0f / s_scale;
        const float w0 = conv_w[r * 3 + 0];
        const float w1 = conv_w[r * 3 + 1];
        const float w2 = conv_w[r * 3 + 2];
        const float bias = conv_b[r];
        const float fr = 0.02f + 0.18f / (1.0f + expf(-frequency[r]));
        const float dc = 0.80f + 0.18f / (1.0f + expf(-decay[r]));
        const float th = 0.35f + 0.75f / (1.0f + expf(-threshold[r]));

        float st = 0.f, vel = 0.f, cnt = 0.f;
        for (int t = 0; t < NTB; ++t) {
            const float cur =
                (sdw[t] * w0 + azw[t] * w1 + elw[t] * w2) * inv_scale + bias;
            vel = dc * vel + cur - fr * st;
            st  = st + fr * vel;
            const float sp = ((st - th) > 0.0f) ? 1.0f : 0.0f;
            st -= sp * th;
            cnt += sp;
        }
        out[(size_t)b * NR + r] = cnt * (1.0f / NTB);
    }
}

extern "C" void kernel_launch(void* const* d_in, const int* in_sizes, int n_in,
                              void* d_out, int out_size, void* d_ws, size_t ws_size,
                              hipStream_t stream) {
    const float* transmit  = (const float*)d_in[0];  // (B,C,T)
    const float* receive   = (const float*)d_in[1];  // (B,2,C,T)
    const float* conv_w    = (const float*)d_in[2];  // (R,3)
    const float* conv_b    = (const float*)d_in[3];  // (R,)
    const float* frequency = (const float*)d_in[4];  // (R,)
    const float* decay     = (const float*)d_in[5];  // (R,)
    const float* threshold = (const float*)d_in[6];  // (R,)
    const float* tw        = (const float*)d_in[7];  // scalar
    const float* rw        = (const float*)d_in[8];  // scalar
    float* out  = (float*)d_out;                     // (B,R) f32
    float* part = (float*)d_ws;                      // (B,4,NTB,CS) = 2 MB

    crb_reduce_k1<<<NB * CS, 256, 0, stream>>>(transmit, receive, part);
    crb_scan_k2<<<NB, 128, 0, stream>>>(part, conv_w, conv_b, frequency,
                                        decay, threshold, tw, rw, out);
}